// Round 1
// baseline (3225.665 us; speedup 1.0000x reference)
//
#include <hip/hip_runtime.h>
#include <hip/hip_bf16.h>

#define N_NODES 25000
#define N_EDGES 200000
#define N_GRAPHS 64
#define HID 128
#define DEPTH 5

typedef _Float16 half8 __attribute__((ext_vector_type(8)));
typedef float f32x4 __attribute__((ext_vector_type(4)));

__device__ inline half8 pack8(float4 a, float4 b) {
    half8 r;
    r[0] = (_Float16)a.x; r[1] = (_Float16)a.y; r[2] = (_Float16)a.z; r[3] = (_Float16)a.w;
    r[4] = (_Float16)b.x; r[5] = (_Float16)b.y; r[6] = (_Float16)b.z; r[7] = (_Float16)b.w;
    return r;
}

// ---------------- embed: h = x @ emb_W + emb_b ----------------
__global__ void embed_kernel(const float* __restrict__ x, const float* __restrict__ W,
                             const float* __restrict__ b, float* __restrict__ h) {
    for (int i = blockIdx.x * blockDim.x + threadIdx.x; i < N_NODES * HID;
         i += gridDim.x * blockDim.x) {
        int n = i >> 7, j = i & 127;
        float acc = b[j];
        #pragma unroll
        for (int k = 0; k < 16; k++) acc += x[n * 16 + k] * W[k * 128 + j];
        h[i] = acc;
    }
}

// ---------------- dists ----------------
__global__ void dist_kernel(const float* __restrict__ pos, const int* __restrict__ ei,
                            float* __restrict__ dists) {
    int e = blockIdx.x * blockDim.x + threadIdx.x;
    if (e < N_EDGES) {
        int s = ei[e], d = ei[N_EDGES + e];
        float dx = pos[d * 3 + 0] - pos[s * 3 + 0];
        float dy = pos[d * 3 + 1] - pos[s * 3 + 1];
        float dz = pos[d * 3 + 2] - pos[s * 3 + 2];
        dists[e] = sqrtf(dx * dx + dy * dy + dz * dz);
    }
}

// ---------------- fused edge-MLP + scatter ----------------
// C tile cols: tile t covers columns {s*8+t : s=0..15}; lane holds col c=(lane&15)*8+t.
__global__ __launch_bounds__(256, 1)
void msg_kernel(const float* __restrict__ h, const float* __restrict__ dists,
                const int* __restrict__ src_idx, const int* __restrict__ dst_idx,
                const float* __restrict__ W1, const float* __restrict__ bias1,
                const float* __restrict__ gam1, const float* __restrict__ bet1,
                const float* __restrict__ W2, const float* __restrict__ bias2,
                const float* __restrict__ gam2, const float* __restrict__ bet2,
                float* __restrict__ agg) {
    __shared__ _Float16 sW1[32768];   // [kb(8)][t(8)][lane(64)][j(8)]
    __shared__ _Float16 sW2[16384];   // [kb(4)][t(8)][lane(64)][j(8)]
    __shared__ _Float16 sM1[17408];   // per-wave [32 rows][136] (row pad breaks bank conflicts)
    __shared__ float sw256[128];
    __shared__ float sB[768];

    const int tid = threadIdx.x;
    for (int idx = tid; idx < 256 * 128; idx += 256) {
        int k = idx >> 7, c = idx & 127;
        int s = c >> 3, t = c & 7, kb = k >> 5, kq = (k >> 3) & 3, j = k & 7;
        sW1[((((kb << 3) + t) << 6) + ((kq << 4) | s)) * 8 + j] = (_Float16)W1[idx];
    }
    for (int idx = tid; idx < 128 * 128; idx += 256) {
        int k = idx >> 7, c = idx & 127;
        int s = c >> 3, t = c & 7, kb = k >> 5, kq = (k >> 3) & 3, j = k & 7;
        sW2[((((kb << 3) + t) << 6) + ((kq << 4) | s)) * 8 + j] = (_Float16)W2[idx];
    }
    if (tid < 128) {
        sw256[tid] = W1[256 * 128 + tid];
        sB[tid] = bias1[tid]; sB[128 + tid] = gam1[tid]; sB[256 + tid] = bet1[tid];
        sB[384 + tid] = bias2[tid]; sB[512 + tid] = gam2[tid]; sB[640 + tid] = bet2[tid];
    }
    __syncthreads();

    const int w = tid >> 6, lane = tid & 63, quad = lane >> 4, s = lane & 15;
    _Float16* myM1 = &sM1[w * (32 * 136)];

    float b1c[8], g1c[8], be1c[8], b2c[8], g2c[8], be2c[8], w256c[8];
    #pragma unroll
    for (int t = 0; t < 8; t++) {
        int c = s * 8 + t;
        b1c[t] = sB[c]; g1c[t] = sB[128 + c]; be1c[t] = sB[256 + c];
        b2c[t] = sB[384 + c]; g2c[t] = sB[512 + c]; be2c[t] = sB[640 + c];
        w256c[t] = sw256[c];
    }

    const int ntiles = (N_EDGES + 127) >> 7;
    for (int tile = blockIdx.x; tile < ntiles; tile += gridDim.x) {
        const int base = (tile << 7) + (w << 5);
        int dstA[2], srcA[2];
        #pragma unroll
        for (int mt = 0; mt < 2; mt++) {
            int e = base + mt * 16 + s; if (e >= N_EDGES) e = N_EDGES - 1;
            dstA[mt] = dst_idx[e]; srcA[mt] = src_idx[e];
        }
        f32x4 acc[2][8];
        #pragma unroll
        for (int mt = 0; mt < 2; mt++)
            #pragma unroll
            for (int t = 0; t < 8; t++) { f32x4 z = {0.f, 0.f, 0.f, 0.f}; acc[mt][t] = z; }

        #pragma unroll
        for (int kb = 0; kb < 8; kb++) {
            half8 af[2];
            #pragma unroll
            for (int mt = 0; mt < 2; mt++) {
                const float* rp = (kb < 4) ? (h + dstA[mt] * 128 + kb * 32)
                                           : (h + srcA[mt] * 128 + (kb - 4) * 32);
                float4 a0 = *(const float4*)(rp + quad * 8);
                float4 a1 = *(const float4*)(rp + quad * 8 + 4);
                af[mt] = pack8(a0, a1);
            }
            #pragma unroll
            for (int t = 0; t < 8; t++) {
                half8 bf = *(const half8*)(&sW1[(((kb << 3) + t) * 64 + lane) * 8]);
                acc[0][t] = __builtin_amdgcn_mfma_f32_16x16x32_f16(af[0], bf, acc[0][t], 0, 0, 0);
                acc[1][t] = __builtin_amdgcn_mfma_f32_16x16x32_f16(af[1], bf, acc[1][t], 0, 0, 0);
            }
        }

        // epilogue 1: +bias +dist*W1[256] ; LN ; relu ; -> myM1 (A-layout-friendly)
        #pragma unroll
        for (int mt = 0; mt < 2; mt++) {
            #pragma unroll
            for (int r = 0; r < 4; r++) {
                int e = base + mt * 16 + quad * 4 + r;
                int ec = (e >= N_EDGES) ? (N_EDGES - 1) : e;
                float dist = dists[ec];
                float v[8], sum = 0.f, sq = 0.f;
                #pragma unroll
                for (int t = 0; t < 8; t++) {
                    v[t] = acc[mt][t][r] + b1c[t] + dist * w256c[t];
                    sum += v[t]; sq += v[t] * v[t];
                }
                #pragma unroll
                for (int m = 1; m < 16; m <<= 1) {
                    sum += __shfl_xor(sum, m, 64);
                    sq  += __shfl_xor(sq, m, 64);
                }
                float mean = sum * (1.f / 128.f);
                float var = sq * (1.f / 128.f) - mean * mean;
                float rstd = rsqrtf(var + 1e-5f);
                half8 hv;
                #pragma unroll
                for (int t = 0; t < 8; t++) {
                    float y = (v[t] - mean) * rstd * g1c[t] + be1c[t];
                    hv[t] = (_Float16)fmaxf(y, 0.f);
                }
                *(half8*)(&myM1[(mt * 16 + quad * 4 + r) * 136 + s * 8]) = hv;
            }
        }
        __syncthreads();

        // GEMM2: m1 @ W2
        f32x4 acc2[2][8];
        #pragma unroll
        for (int mt = 0; mt < 2; mt++)
            #pragma unroll
            for (int t = 0; t < 8; t++) { f32x4 z = {0.f, 0.f, 0.f, 0.f}; acc2[mt][t] = z; }
        #pragma unroll
        for (int kb = 0; kb < 4; kb++) {
            half8 af[2];
            #pragma unroll
            for (int mt = 0; mt < 2; mt++)
                af[mt] = *(const half8*)(&myM1[(mt * 16 + s) * 136 + kb * 32 + quad * 8]);
            #pragma unroll
            for (int t = 0; t < 8; t++) {
                half8 bf = *(const half8*)(&sW2[(((kb << 3) + t) * 64 + lane) * 8]);
                acc2[0][t] = __builtin_amdgcn_mfma_f32_16x16x32_f16(af[0], bf, acc2[0][t], 0, 0, 0);
                acc2[1][t] = __builtin_amdgcn_mfma_f32_16x16x32_f16(af[1], bf, acc2[1][t], 0, 0, 0);
            }
        }

        // epilogue 2: +bias ; LN ; relu ; atomic scatter to agg[dst]
        #pragma unroll
        for (int mt = 0; mt < 2; mt++) {
            #pragma unroll
            for (int r = 0; r < 4; r++) {
                int e = base + mt * 16 + quad * 4 + r;
                float v[8], sum = 0.f, sq = 0.f;
                #pragma unroll
                for (int t = 0; t < 8; t++) {
                    v[t] = acc2[mt][t][r] + b2c[t];
                    sum += v[t]; sq += v[t] * v[t];
                }
                #pragma unroll
                for (int m = 1; m < 16; m <<= 1) {
                    sum += __shfl_xor(sum, m, 64);
                    sq  += __shfl_xor(sq, m, 64);
                }
                float mean = sum * (1.f / 128.f);
                float var = sq * (1.f / 128.f) - mean * mean;
                float rstd = rsqrtf(var + 1e-5f);
                if (e < N_EDGES) {
                    int d = dst_idx[e];
                    float* ap = agg + (size_t)d * 128 + s * 8;
                    #pragma unroll
                    for (int t = 0; t < 8; t++) {
                        float y = (v[t] - mean) * rstd * g2c[t] + be2c[t];
                        y = fmaxf(y, 0.f);
                        if (y != 0.f) atomicAdd(ap + t, y);
                    }
                }
            }
        }
        __syncthreads();
    }
}

// ---------------- fused node-MLP + residual ----------------
__global__ __launch_bounds__(256, 1)
void upd_kernel(float* __restrict__ h, const float* __restrict__ agg,
                const float* __restrict__ W1, const float* __restrict__ bias1,
                const float* __restrict__ gam1, const float* __restrict__ bet1,
                const float* __restrict__ W2, const float* __restrict__ bias2,
                const float* __restrict__ gam2, const float* __restrict__ bet2) {
    __shared__ _Float16 sW1[32768];
    __shared__ _Float16 sW2[16384];
    __shared__ _Float16 sM1[17408];
    __shared__ float sB[768];

    const int tid = threadIdx.x;
    for (int idx = tid; idx < 256 * 128; idx += 256) {
        int k = idx >> 7, c = idx & 127;
        int s = c >> 3, t = c & 7, kb = k >> 5, kq = (k >> 3) & 3, j = k & 7;
        sW1[((((kb << 3) + t) << 6) + ((kq << 4) | s)) * 8 + j] = (_Float16)W1[idx];
    }
    for (int idx = tid; idx < 128 * 128; idx += 256) {
        int k = idx >> 7, c = idx & 127;
        int s = c >> 3, t = c & 7, kb = k >> 5, kq = (k >> 3) & 3, j = k & 7;
        sW2[((((kb << 3) + t) << 6) + ((kq << 4) | s)) * 8 + j] = (_Float16)W2[idx];
    }
    if (tid < 128) {
        sB[tid] = bias1[tid]; sB[128 + tid] = gam1[tid]; sB[256 + tid] = bet1[tid];
        sB[384 + tid] = bias2[tid]; sB[512 + tid] = gam2[tid]; sB[640 + tid] = bet2[tid];
    }
    __syncthreads();

    const int w = tid >> 6, lane = tid & 63, quad = lane >> 4, s = lane & 15;
    _Float16* myM1 = &sM1[w * (32 * 136)];

    float b1c[8], g1c[8], be1c[8], b2c[8], g2c[8], be2c[8];
    #pragma unroll
    for (int t = 0; t < 8; t++) {
        int c = s * 8 + t;
        b1c[t] = sB[c]; g1c[t] = sB[128 + c]; be1c[t] = sB[256 + c];
        b2c[t] = sB[384 + c]; g2c[t] = sB[512 + c]; be2c[t] = sB[640 + c];
    }

    const int ntiles = (N_NODES + 127) >> 7;
    for (int tile = blockIdx.x; tile < ntiles; tile += gridDim.x) {
        const int base = (tile << 7) + (w << 5);
        int nA[2];
        #pragma unroll
        for (int mt = 0; mt < 2; mt++) {
            int n = base + mt * 16 + s; if (n >= N_NODES) n = N_NODES - 1;
            nA[mt] = n;
        }
        f32x4 acc[2][8];
        #pragma unroll
        for (int mt = 0; mt < 2; mt++)
            #pragma unroll
            for (int t = 0; t < 8; t++) { f32x4 z = {0.f, 0.f, 0.f, 0.f}; acc[mt][t] = z; }

        #pragma unroll
        for (int kb = 0; kb < 8; kb++) {
            half8 af[2];
            #pragma unroll
            for (int mt = 0; mt < 2; mt++) {
                const float* rp = (kb < 4) ? (h + nA[mt] * 128 + kb * 32)
                                           : (agg + nA[mt] * 128 + (kb - 4) * 32);
                float4 a0 = *(const float4*)(rp + quad * 8);
                float4 a1 = *(const float4*)(rp + quad * 8 + 4);
                af[mt] = pack8(a0, a1);
            }
            #pragma unroll
            for (int t = 0; t < 8; t++) {
                half8 bf = *(const half8*)(&sW1[(((kb << 3) + t) * 64 + lane) * 8]);
                acc[0][t] = __builtin_amdgcn_mfma_f32_16x16x32_f16(af[0], bf, acc[0][t], 0, 0, 0);
                acc[1][t] = __builtin_amdgcn_mfma_f32_16x16x32_f16(af[1], bf, acc[1][t], 0, 0, 0);
            }
        }

        #pragma unroll
        for (int mt = 0; mt < 2; mt++) {
            #pragma unroll
            for (int r = 0; r < 4; r++) {
                float v[8], sum = 0.f, sq = 0.f;
                #pragma unroll
                for (int t = 0; t < 8; t++) {
                    v[t] = acc[mt][t][r] + b1c[t];
                    sum += v[t]; sq += v[t] * v[t];
                }
                #pragma unroll
                for (int m = 1; m < 16; m <<= 1) {
                    sum += __shfl_xor(sum, m, 64);
                    sq  += __shfl_xor(sq, m, 64);
                }
                float mean = sum * (1.f / 128.f);
                float var = sq * (1.f / 128.f) - mean * mean;
                float rstd = rsqrtf(var + 1e-5f);
                half8 hv;
                #pragma unroll
                for (int t = 0; t < 8; t++) {
                    float y = (v[t] - mean) * rstd * g1c[t] + be1c[t];
                    hv[t] = (_Float16)fmaxf(y, 0.f);
                }
                *(half8*)(&myM1[(mt * 16 + quad * 4 + r) * 136 + s * 8]) = hv;
            }
        }
        __syncthreads();

        f32x4 acc2[2][8];
        #pragma unroll
        for (int mt = 0; mt < 2; mt++)
            #pragma unroll
            for (int t = 0; t < 8; t++) { f32x4 z = {0.f, 0.f, 0.f, 0.f}; acc2[mt][t] = z; }
        #pragma unroll
        for (int kb = 0; kb < 4; kb++) {
            half8 af[2];
            #pragma unroll
            for (int mt = 0; mt < 2; mt++)
                af[mt] = *(const half8*)(&myM1[(mt * 16 + s) * 136 + kb * 32 + quad * 8]);
            #pragma unroll
            for (int t = 0; t < 8; t++) {
                half8 bf = *(const half8*)(&sW2[(((kb << 3) + t) * 64 + lane) * 8]);
                acc2[0][t] = __builtin_amdgcn_mfma_f32_16x16x32_f16(af[0], bf, acc2[0][t], 0, 0, 0);
                acc2[1][t] = __builtin_amdgcn_mfma_f32_16x16x32_f16(af[1], bf, acc2[1][t], 0, 0, 0);
            }
        }

        // epilogue 2: LN ; relu ; h += u
        #pragma unroll
        for (int mt = 0; mt < 2; mt++) {
            #pragma unroll
            for (int r = 0; r < 4; r++) {
                int n = base + mt * 16 + quad * 4 + r;
                float v[8], sum = 0.f, sq = 0.f;
                #pragma unroll
                for (int t = 0; t < 8; t++) {
                    v[t] = acc2[mt][t][r] + b2c[t];
                    sum += v[t]; sq += v[t] * v[t];
                }
                #pragma unroll
                for (int m = 1; m < 16; m <<= 1) {
                    sum += __shfl_xor(sum, m, 64);
                    sq  += __shfl_xor(sq, m, 64);
                }
                float mean = sum * (1.f / 128.f);
                float var = sq * (1.f / 128.f) - mean * mean;
                float rstd = rsqrtf(var + 1e-5f);
                if (n < N_NODES) {
                    float* hp = h + (size_t)n * 128 + s * 8;
                    float4 h0 = *(float4*)hp;
                    float4 h1 = *(float4*)(hp + 4);
                    float y[8];
                    #pragma unroll
                    for (int t = 0; t < 8; t++) {
                        float u = (v[t] - mean) * rstd * g2c[t] + be2c[t];
                        y[t] = fmaxf(u, 0.f);
                    }
                    h0.x += y[0]; h0.y += y[1]; h0.z += y[2]; h0.w += y[3];
                    h1.x += y[4]; h1.y += y[5]; h1.z += y[6]; h1.w += y[7];
                    *(float4*)hp = h0;
                    *(float4*)(hp + 4) = h1;
                }
            }
        }
        __syncthreads();
    }
}

// ---------------- pool: g[b] = sum_{batch[n]==b} h[n] ----------------
__device__ inline int lbound(const int* a, int n, int key) {
    int lo = 0, hi = n;
    while (lo < hi) { int mid = (lo + hi) >> 1; if (a[mid] < key) lo = mid + 1; else hi = mid; }
    return lo;
}

__global__ void pool_kernel(const float* __restrict__ h, const int* __restrict__ batch,
                            float* __restrict__ g) {
    int b = blockIdx.x, j = threadIdx.x;  // 64 blocks x 128 threads
    int lo = lbound(batch, N_NODES, b), hi = lbound(batch, N_NODES, b + 1);
    float sum = 0.f;
    for (int n = lo; n < hi; n++) sum += h[(size_t)n * 128 + j];
    g[b * 128 + j] = sum;
}

// ---------------- pred: relu(g@W1+b1)@W2+b2 ----------------
__global__ void pred_kernel(const float* __restrict__ g, const float* __restrict__ W1,
                            const float* __restrict__ b1, const float* __restrict__ W2,
                            const float* __restrict__ b2, float* __restrict__ out) {
    int b = blockIdx.x, j = threadIdx.x;  // 64 blocks x 128 threads
    float t = b1[j];
    for (int k = 0; k < 128; k++) t += g[b * 128 + k] * W1[k * 128 + j];
    t = fmaxf(t, 0.f);
    __shared__ float red[128];
    red[j] = t * W2[j];
    __syncthreads();
    for (int off = 64; off > 0; off >>= 1) {
        if (j < off) red[j] += red[j + off];
        __syncthreads();
    }
    if (j == 0) out[b] = red[0] + b2[0];
}

extern "C" void kernel_launch(void* const* d_in, const int* in_sizes, int n_in,
                              void* d_out, int out_size, void* d_ws, size_t ws_size,
                              hipStream_t stream) {
    const float* x      = (const float*)d_in[0];
    const float* pos    = (const float*)d_in[1];
    const int*   ei     = (const int*)d_in[2];
    const int*   batch  = (const int*)d_in[3];
    const float* emb_W  = (const float*)d_in[4];
    const float* emb_b  = (const float*)d_in[5];
    const float* msg_W1 = (const float*)d_in[6];
    const float* msg_b1 = (const float*)d_in[7];
    const float* msg_W2 = (const float*)d_in[8];
    const float* msg_b2 = (const float*)d_in[9];
    const float* upd_W1 = (const float*)d_in[10];
    const float* upd_b1 = (const float*)d_in[11];
    const float* upd_W2 = (const float*)d_in[12];
    const float* upd_b2 = (const float*)d_in[13];
    const float* msg_g1 = (const float*)d_in[14];
    const float* msg_be1= (const float*)d_in[15];
    const float* msg_g2 = (const float*)d_in[16];
    const float* msg_be2= (const float*)d_in[17];
    const float* upd_g1 = (const float*)d_in[18];
    const float* upd_be1= (const float*)d_in[19];
    const float* upd_g2 = (const float*)d_in[20];
    const float* upd_be2= (const float*)d_in[21];
    const float* pred_W1= (const float*)d_in[22];
    const float* pred_b1= (const float*)d_in[23];
    const float* pred_W2= (const float*)d_in[24];
    const float* pred_b2= (const float*)d_in[25];
    float* out = (float*)d_out;

    float* ws    = (float*)d_ws;
    float* h     = ws;                 // N*128
    float* agg   = ws + 3200000;       // N*128
    float* dists = ws + 6400000;       // E
    float* g     = ws + 6600000;       // 64*128

    embed_kernel<<<4096, 256, 0, stream>>>(x, emb_W, emb_b, h);
    dist_kernel<<<(N_EDGES + 255) / 256, 256, 0, stream>>>(pos, ei, dists);

    for (int l = 0; l < DEPTH; l++) {
        hipMemsetAsync(agg, 0, (size_t)N_NODES * 128 * sizeof(float), stream);
        msg_kernel<<<256, 256, 0, stream>>>(
            h, dists, ei, ei + N_EDGES,
            msg_W1 + (size_t)l * 257 * 128, msg_b1 + l * 128, msg_g1 + l * 128, msg_be1 + l * 128,
            msg_W2 + (size_t)l * 128 * 128, msg_b2 + l * 128, msg_g2 + l * 128, msg_be2 + l * 128,
            agg);
        upd_kernel<<<196, 256, 0, stream>>>(
            h, agg,
            upd_W1 + (size_t)l * 256 * 128, upd_b1 + l * 128, upd_g1 + l * 128, upd_be1 + l * 128,
            upd_W2 + (size_t)l * 128 * 128, upd_b2 + l * 128, upd_g2 + l * 128, upd_be2 + l * 128);
    }

    pool_kernel<<<64, 128, 0, stream>>>(h, batch, g);
    pred_kernel<<<64, 128, 0, stream>>>(g, pred_W1, pred_b1, pred_W2, pred_b2, out);
}

// Round 2
// 1256.513 us; speedup vs baseline: 2.5672x; 2.5672x over previous
//
#include <hip/hip_runtime.h>
#include <hip/hip_bf16.h>

#define N_NODES 25000
#define N_EDGES 200000
#define N_GRAPHS 64
#define HID 128
#define DEPTH 5

typedef _Float16 half8 __attribute__((ext_vector_type(8)));
typedef float f32x4 __attribute__((ext_vector_type(4)));

__device__ inline half8 pack8(float4 a, float4 b) {
    half8 r;
    r[0] = (_Float16)a.x; r[1] = (_Float16)a.y; r[2] = (_Float16)a.z; r[3] = (_Float16)a.w;
    r[4] = (_Float16)b.x; r[5] = (_Float16)b.y; r[6] = (_Float16)b.z; r[7] = (_Float16)b.w;
    return r;
}

// ---------------- embed: h = x @ emb_W + emb_b ----------------
__global__ void embed_kernel(const float* __restrict__ x, const float* __restrict__ W,
                             const float* __restrict__ b, float* __restrict__ h) {
    for (int i = blockIdx.x * blockDim.x + threadIdx.x; i < N_NODES * HID;
         i += gridDim.x * blockDim.x) {
        int n = i >> 7, j = i & 127;
        float acc = b[j];
        #pragma unroll
        for (int k = 0; k < 16; k++) acc += x[n * 16 + k] * W[k * 128 + j];
        h[i] = acc;
    }
}

// ---------------- CSR build: histogram / scan / scatter(+dist) ----------------
__global__ void hist_kernel(const int* __restrict__ ei, int* __restrict__ cnt) {
    int e = blockIdx.x * blockDim.x + threadIdx.x;
    if (e < N_EDGES) atomicAdd(&cnt[ei[N_EDGES + e]], 1);
}

__global__ void scan_kernel(const int* __restrict__ cnt, int* __restrict__ rowptr,
                            int* __restrict__ cursor) {
    __shared__ int sdata[256];
    __shared__ int carry;
    if (threadIdx.x == 0) carry = 0;
    __syncthreads();
    for (int base = 0; base < N_NODES; base += 256) {
        int i = base + threadIdx.x;
        int v = (i < N_NODES) ? cnt[i] : 0;
        sdata[threadIdx.x] = v;
        __syncthreads();
        #pragma unroll
        for (int off = 1; off < 256; off <<= 1) {
            int t = (threadIdx.x >= off) ? sdata[threadIdx.x - off] : 0;
            __syncthreads();
            sdata[threadIdx.x] += t;
            __syncthreads();
        }
        int excl = sdata[threadIdx.x] - v + carry;
        if (i < N_NODES) { rowptr[i] = excl; cursor[i] = excl; }
        __syncthreads();
        if (threadIdx.x == 255) carry += sdata[255];
        __syncthreads();
    }
    if (threadIdx.x == 0) rowptr[N_NODES] = carry;
}

__global__ void scatter_kernel(const int* __restrict__ ei, const float* __restrict__ pos,
                               int* __restrict__ cursor, int* __restrict__ src_s,
                               int* __restrict__ dst_s, float* __restrict__ dist_s) {
    int e = blockIdx.x * blockDim.x + threadIdx.x;
    if (e < N_EDGES) {
        int s = ei[e], d = ei[N_EDGES + e];
        int p = atomicAdd(&cursor[d], 1);
        src_s[p] = s; dst_s[p] = d;
        float dx = pos[d * 3 + 0] - pos[s * 3 + 0];
        float dy = pos[d * 3 + 1] - pos[s * 3 + 1];
        float dz = pos[d * 3 + 2] - pos[s * 3 + 2];
        dist_s[p] = sqrtf(dx * dx + dy * dy + dz * dz);
    }
}

// ---------------- fused edge-MLP (dst-sorted, writes m2 f16) ----------------
__global__ __launch_bounds__(256, 1)
void msg_kernel(const float* __restrict__ h, const float* __restrict__ dist_s,
                const int* __restrict__ src_s, const int* __restrict__ dst_s,
                const float* __restrict__ W1, const float* __restrict__ bias1,
                const float* __restrict__ gam1, const float* __restrict__ bet1,
                const float* __restrict__ W2, const float* __restrict__ bias2,
                const float* __restrict__ gam2, const float* __restrict__ bet2,
                _Float16* __restrict__ m2) {
    __shared__ _Float16 sW1[32768];   // [kb(8)][t(8)][lane(64)][j(8)]
    __shared__ _Float16 sW2[16384];   // [kb(4)][t(8)][lane(64)][j(8)]
    __shared__ _Float16 sM1[17408];   // per-wave [32 rows][136]
    __shared__ float sw256[128];
    __shared__ float sB[768];

    const int tid = threadIdx.x;
    for (int idx = tid; idx < 256 * 128; idx += 256) {
        int k = idx >> 7, c = idx & 127;
        int s = c >> 3, t = c & 7, kb = k >> 5, kq = (k >> 3) & 3, j = k & 7;
        sW1[((((kb << 3) + t) << 6) + ((kq << 4) | s)) * 8 + j] = (_Float16)W1[idx];
    }
    for (int idx = tid; idx < 128 * 128; idx += 256) {
        int k = idx >> 7, c = idx & 127;
        int s = c >> 3, t = c & 7, kb = k >> 5, kq = (k >> 3) & 3, j = k & 7;
        sW2[((((kb << 3) + t) << 6) + ((kq << 4) | s)) * 8 + j] = (_Float16)W2[idx];
    }
    if (tid < 128) {
        sw256[tid] = W1[256 * 128 + tid];
        sB[tid] = bias1[tid]; sB[128 + tid] = gam1[tid]; sB[256 + tid] = bet1[tid];
        sB[384 + tid] = bias2[tid]; sB[512 + tid] = gam2[tid]; sB[640 + tid] = bet2[tid];
    }
    __syncthreads();

    const int w = tid >> 6, lane = tid & 63, quad = lane >> 4, s = lane & 15;
    _Float16* myM1 = &sM1[w * (32 * 136)];

    float b1c[8], g1c[8], be1c[8], b2c[8], g2c[8], be2c[8], w256c[8];
    #pragma unroll
    for (int t = 0; t < 8; t++) {
        int c = s * 8 + t;
        b1c[t] = sB[c]; g1c[t] = sB[128 + c]; be1c[t] = sB[256 + c];
        b2c[t] = sB[384 + c]; g2c[t] = sB[512 + c]; be2c[t] = sB[640 + c];
        w256c[t] = sw256[c];
    }

    const int ntiles = (N_EDGES + 127) >> 7;
    for (int tile = blockIdx.x; tile < ntiles; tile += gridDim.x) {
        const int base = (tile << 7) + (w << 5);
        int dstA[2], srcA[2];
        #pragma unroll
        for (int mt = 0; mt < 2; mt++) {
            int e = base + mt * 16 + s; if (e >= N_EDGES) e = N_EDGES - 1;
            dstA[mt] = dst_s[e]; srcA[mt] = src_s[e];
        }
        f32x4 acc[2][8];
        #pragma unroll
        for (int mt = 0; mt < 2; mt++)
            #pragma unroll
            for (int t = 0; t < 8; t++) { f32x4 z = {0.f, 0.f, 0.f, 0.f}; acc[mt][t] = z; }

        #pragma unroll
        for (int kb = 0; kb < 8; kb++) {
            half8 af[2];
            #pragma unroll
            for (int mt = 0; mt < 2; mt++) {
                const float* rp = (kb < 4) ? (h + (size_t)dstA[mt] * 128 + kb * 32)
                                           : (h + (size_t)srcA[mt] * 128 + (kb - 4) * 32);
                float4 a0 = *(const float4*)(rp + quad * 8);
                float4 a1 = *(const float4*)(rp + quad * 8 + 4);
                af[mt] = pack8(a0, a1);
            }
            #pragma unroll
            for (int t = 0; t < 8; t++) {
                half8 bf = *(const half8*)(&sW1[(((kb << 3) + t) * 64 + lane) * 8]);
                acc[0][t] = __builtin_amdgcn_mfma_f32_16x16x32_f16(af[0], bf, acc[0][t], 0, 0, 0);
                acc[1][t] = __builtin_amdgcn_mfma_f32_16x16x32_f16(af[1], bf, acc[1][t], 0, 0, 0);
            }
        }

        // epilogue 1: +bias +dist*W1[256] ; LN ; relu ; -> myM1
        #pragma unroll
        for (int mt = 0; mt < 2; mt++) {
            #pragma unroll
            for (int r = 0; r < 4; r++) {
                int e = base + mt * 16 + quad * 4 + r;
                int ec = (e >= N_EDGES) ? (N_EDGES - 1) : e;
                float dist = dist_s[ec];
                float v[8], sum = 0.f, sq = 0.f;
                #pragma unroll
                for (int t = 0; t < 8; t++) {
                    v[t] = acc[mt][t][r] + b1c[t] + dist * w256c[t];
                    sum += v[t]; sq += v[t] * v[t];
                }
                #pragma unroll
                for (int m = 1; m < 16; m <<= 1) {
                    sum += __shfl_xor(sum, m, 64);
                    sq  += __shfl_xor(sq, m, 64);
                }
                float mean = sum * (1.f / 128.f);
                float var = sq * (1.f / 128.f) - mean * mean;
                float rstd = rsqrtf(var + 1e-5f);
                half8 hv;
                #pragma unroll
                for (int t = 0; t < 8; t++) {
                    float y = (v[t] - mean) * rstd * g1c[t] + be1c[t];
                    hv[t] = (_Float16)fmaxf(y, 0.f);
                }
                *(half8*)(&myM1[(mt * 16 + quad * 4 + r) * 136 + s * 8]) = hv;
            }
        }
        __syncthreads();

        // GEMM2: m1 @ W2
        f32x4 acc2[2][8];
        #pragma unroll
        for (int mt = 0; mt < 2; mt++)
            #pragma unroll
            for (int t = 0; t < 8; t++) { f32x4 z = {0.f, 0.f, 0.f, 0.f}; acc2[mt][t] = z; }
        #pragma unroll
        for (int kb = 0; kb < 4; kb++) {
            half8 af[2];
            #pragma unroll
            for (int mt = 0; mt < 2; mt++)
                af[mt] = *(const half8*)(&myM1[(mt * 16 + s) * 136 + kb * 32 + quad * 8]);
            #pragma unroll
            for (int t = 0; t < 8; t++) {
                half8 bf = *(const half8*)(&sW2[(((kb << 3) + t) * 64 + lane) * 8]);
                acc2[0][t] = __builtin_amdgcn_mfma_f32_16x16x32_f16(af[0], bf, acc2[0][t], 0, 0, 0);
                acc2[1][t] = __builtin_amdgcn_mfma_f32_16x16x32_f16(af[1], bf, acc2[1][t], 0, 0, 0);
            }
        }

        // epilogue 2: +bias ; LN ; relu ; plain store to m2[e]
        #pragma unroll
        for (int mt = 0; mt < 2; mt++) {
            #pragma unroll
            for (int r = 0; r < 4; r++) {
                int e = base + mt * 16 + quad * 4 + r;
                float v[8], sum = 0.f, sq = 0.f;
                #pragma unroll
                for (int t = 0; t < 8; t++) {
                    v[t] = acc2[mt][t][r] + b2c[t];
                    sum += v[t]; sq += v[t] * v[t];
                }
                #pragma unroll
                for (int m = 1; m < 16; m <<= 1) {
                    sum += __shfl_xor(sum, m, 64);
                    sq  += __shfl_xor(sq, m, 64);
                }
                float mean = sum * (1.f / 128.f);
                float var = sq * (1.f / 128.f) - mean * mean;
                float rstd = rsqrtf(var + 1e-5f);
                if (e < N_EDGES) {
                    half8 hv;
                    #pragma unroll
                    for (int t = 0; t < 8; t++) {
                        float y = (v[t] - mean) * rstd * g2c[t] + be2c[t];
                        hv[t] = (_Float16)fmaxf(y, 0.f);
                    }
                    *(half8*)(&m2[(size_t)e * 128 + s * 8]) = hv;
                }
            }
        }
        __syncthreads();
    }
}

// ---------------- agg: segmented sum of m2 per dst node ----------------
__global__ void agg_kernel(const _Float16* __restrict__ m2, const int* __restrict__ rowptr,
                           float* __restrict__ agg) {
    int n = blockIdx.x, j = threadIdx.x;  // 25000 blocks x 128 threads
    int lo = rowptr[n], hi = rowptr[n + 1];
    float s = 0.f;
    for (int r = lo; r < hi; r++) s += (float)m2[(size_t)r * 128 + j];
    agg[(size_t)n * 128 + j] = s;
}

// ---------------- fused node-MLP + residual ----------------
__global__ __launch_bounds__(256, 1)
void upd_kernel(float* __restrict__ h, const float* __restrict__ agg,
                const float* __restrict__ W1, const float* __restrict__ bias1,
                const float* __restrict__ gam1, const float* __restrict__ bet1,
                const float* __restrict__ W2, const float* __restrict__ bias2,
                const float* __restrict__ gam2, const float* __restrict__ bet2) {
    __shared__ _Float16 sW1[32768];
    __shared__ _Float16 sW2[16384];
    __shared__ _Float16 sM1[17408];
    __shared__ float sB[768];

    const int tid = threadIdx.x;
    for (int idx = tid; idx < 256 * 128; idx += 256) {
        int k = idx >> 7, c = idx & 127;
        int s = c >> 3, t = c & 7, kb = k >> 5, kq = (k >> 3) & 3, j = k & 7;
        sW1[((((kb << 3) + t) << 6) + ((kq << 4) | s)) * 8 + j] = (_Float16)W1[idx];
    }
    for (int idx = tid; idx < 128 * 128; idx += 256) {
        int k = idx >> 7, c = idx & 127;
        int s = c >> 3, t = c & 7, kb = k >> 5, kq = (k >> 3) & 3, j = k & 7;
        sW2[((((kb << 3) + t) << 6) + ((kq << 4) | s)) * 8 + j] = (_Float16)W2[idx];
    }
    if (tid < 128) {
        sB[tid] = bias1[tid]; sB[128 + tid] = gam1[tid]; sB[256 + tid] = bet1[tid];
        sB[384 + tid] = bias2[tid]; sB[512 + tid] = gam2[tid]; sB[640 + tid] = bet2[tid];
    }
    __syncthreads();

    const int w = tid >> 6, lane = tid & 63, quad = lane >> 4, s = lane & 15;
    _Float16* myM1 = &sM1[w * (32 * 136)];

    float b1c[8], g1c[8], be1c[8], b2c[8], g2c[8], be2c[8];
    #pragma unroll
    for (int t = 0; t < 8; t++) {
        int c = s * 8 + t;
        b1c[t] = sB[c]; g1c[t] = sB[128 + c]; be1c[t] = sB[256 + c];
        b2c[t] = sB[384 + c]; g2c[t] = sB[512 + c]; be2c[t] = sB[640 + c];
    }

    const int ntiles = (N_NODES + 127) >> 7;
    for (int tile = blockIdx.x; tile < ntiles; tile += gridDim.x) {
        const int base = (tile << 7) + (w << 5);
        int nA[2];
        #pragma unroll
        for (int mt = 0; mt < 2; mt++) {
            int n = base + mt * 16 + s; if (n >= N_NODES) n = N_NODES - 1;
            nA[mt] = n;
        }
        f32x4 acc[2][8];
        #pragma unroll
        for (int mt = 0; mt < 2; mt++)
            #pragma unroll
            for (int t = 0; t < 8; t++) { f32x4 z = {0.f, 0.f, 0.f, 0.f}; acc[mt][t] = z; }

        #pragma unroll
        for (int kb = 0; kb < 8; kb++) {
            half8 af[2];
            #pragma unroll
            for (int mt = 0; mt < 2; mt++) {
                const float* rp = (kb < 4) ? (h + (size_t)nA[mt] * 128 + kb * 32)
                                           : (agg + (size_t)nA[mt] * 128 + (kb - 4) * 32);
                float4 a0 = *(const float4*)(rp + quad * 8);
                float4 a1 = *(const float4*)(rp + quad * 8 + 4);
                af[mt] = pack8(a0, a1);
            }
            #pragma unroll
            for (int t = 0; t < 8; t++) {
                half8 bf = *(const half8*)(&sW1[(((kb << 3) + t) * 64 + lane) * 8]);
                acc[0][t] = __builtin_amdgcn_mfma_f32_16x16x32_f16(af[0], bf, acc[0][t], 0, 0, 0);
                acc[1][t] = __builtin_amdgcn_mfma_f32_16x16x32_f16(af[1], bf, acc[1][t], 0, 0, 0);
            }
        }

        #pragma unroll
        for (int mt = 0; mt < 2; mt++) {
            #pragma unroll
            for (int r = 0; r < 4; r++) {
                float v[8], sum = 0.f, sq = 0.f;
                #pragma unroll
                for (int t = 0; t < 8; t++) {
                    v[t] = acc[mt][t][r] + b1c[t];
                    sum += v[t]; sq += v[t] * v[t];
                }
                #pragma unroll
                for (int m = 1; m < 16; m <<= 1) {
                    sum += __shfl_xor(sum, m, 64);
                    sq  += __shfl_xor(sq, m, 64);
                }
                float mean = sum * (1.f / 128.f);
                float var = sq * (1.f / 128.f) - mean * mean;
                float rstd = rsqrtf(var + 1e-5f);
                half8 hv;
                #pragma unroll
                for (int t = 0; t < 8; t++) {
                    float y = (v[t] - mean) * rstd * g1c[t] + be1c[t];
                    hv[t] = (_Float16)fmaxf(y, 0.f);
                }
                *(half8*)(&myM1[(mt * 16 + quad * 4 + r) * 136 + s * 8]) = hv;
            }
        }
        __syncthreads();

        f32x4 acc2[2][8];
        #pragma unroll
        for (int mt = 0; mt < 2; mt++)
            #pragma unroll
            for (int t = 0; t < 8; t++) { f32x4 z = {0.f, 0.f, 0.f, 0.f}; acc2[mt][t] = z; }
        #pragma unroll
        for (int kb = 0; kb < 4; kb++) {
            half8 af[2];
            #pragma unroll
            for (int mt = 0; mt < 2; mt++)
                af[mt] = *(const half8*)(&myM1[(mt * 16 + s) * 136 + kb * 32 + quad * 8]);
            #pragma unroll
            for (int t = 0; t < 8; t++) {
                half8 bf = *(const half8*)(&sW2[(((kb << 3) + t) * 64 + lane) * 8]);
                acc2[0][t] = __builtin_amdgcn_mfma_f32_16x16x32_f16(af[0], bf, acc2[0][t], 0, 0, 0);
                acc2[1][t] = __builtin_amdgcn_mfma_f32_16x16x32_f16(af[1], bf, acc2[1][t], 0, 0, 0);
            }
        }

        // epilogue 2: LN ; relu ; h += u
        #pragma unroll
        for (int mt = 0; mt < 2; mt++) {
            #pragma unroll
            for (int r = 0; r < 4; r++) {
                int n = base + mt * 16 + quad * 4 + r;
                float v[8], sum = 0.f, sq = 0.f;
                #pragma unroll
                for (int t = 0; t < 8; t++) {
                    v[t] = acc2[mt][t][r] + b2c[t];
                    sum += v[t]; sq += v[t] * v[t];
                }
                #pragma unroll
                for (int m = 1; m < 16; m <<= 1) {
                    sum += __shfl_xor(sum, m, 64);
                    sq  += __shfl_xor(sq, m, 64);
                }
                float mean = sum * (1.f / 128.f);
                float var = sq * (1.f / 128.f) - mean * mean;
                float rstd = rsqrtf(var + 1e-5f);
                if (n < N_NODES) {
                    float* hp = h + (size_t)n * 128 + s * 8;
                    float4 h0 = *(float4*)hp;
                    float4 h1 = *(float4*)(hp + 4);
                    float y[8];
                    #pragma unroll
                    for (int t = 0; t < 8; t++) {
                        float u = (v[t] - mean) * rstd * g2c[t] + be2c[t];
                        y[t] = fmaxf(u, 0.f);
                    }
                    h0.x += y[0]; h0.y += y[1]; h0.z += y[2]; h0.w += y[3];
                    h1.x += y[4]; h1.y += y[5]; h1.z += y[6]; h1.w += y[7];
                    *(float4*)hp = h0;
                    *(float4*)(hp + 4) = h1;
                }
            }
        }
        __syncthreads();
    }
}

// ---------------- pool ----------------
__device__ inline int lbound(const int* a, int n, int key) {
    int lo = 0, hi = n;
    while (lo < hi) { int mid = (lo + hi) >> 1; if (a[mid] < key) lo = mid + 1; else hi = mid; }
    return lo;
}

__global__ void pool_kernel(const float* __restrict__ h, const int* __restrict__ batch,
                            float* __restrict__ g) {
    int b = blockIdx.x, j = threadIdx.x;
    int lo = lbound(batch, N_NODES, b), hi = lbound(batch, N_NODES, b + 1);
    float sum = 0.f;
    for (int n = lo; n < hi; n++) sum += h[(size_t)n * 128 + j];
    g[b * 128 + j] = sum;
}

// ---------------- pred ----------------
__global__ void pred_kernel(const float* __restrict__ g, const float* __restrict__ W1,
                            const float* __restrict__ b1, const float* __restrict__ W2,
                            const float* __restrict__ b2, float* __restrict__ out) {
    int b = blockIdx.x, j = threadIdx.x;
    float t = b1[j];
    for (int k = 0; k < 128; k++) t += g[b * 128 + k] * W1[k * 128 + j];
    t = fmaxf(t, 0.f);
    __shared__ float red[128];
    red[j] = t * W2[j];
    __syncthreads();
    for (int off = 64; off > 0; off >>= 1) {
        if (j < off) red[j] += red[j + off];
        __syncthreads();
    }
    if (j == 0) out[b] = red[0] + b2[0];
}

extern "C" void kernel_launch(void* const* d_in, const int* in_sizes, int n_in,
                              void* d_out, int out_size, void* d_ws, size_t ws_size,
                              hipStream_t stream) {
    const float* x      = (const float*)d_in[0];
    const float* pos    = (const float*)d_in[1];
    const int*   ei     = (const int*)d_in[2];
    const int*   batch  = (const int*)d_in[3];
    const float* emb_W  = (const float*)d_in[4];
    const float* emb_b  = (const float*)d_in[5];
    const float* msg_W1 = (const float*)d_in[6];
    const float* msg_b1 = (const float*)d_in[7];
    const float* msg_W2 = (const float*)d_in[8];
    const float* msg_b2 = (const float*)d_in[9];
    const float* upd_W1 = (const float*)d_in[10];
    const float* upd_b1 = (const float*)d_in[11];
    const float* upd_W2 = (const float*)d_in[12];
    const float* upd_b2 = (const float*)d_in[13];
    const float* msg_g1 = (const float*)d_in[14];
    const float* msg_be1= (const float*)d_in[15];
    const float* msg_g2 = (const float*)d_in[16];
    const float* msg_be2= (const float*)d_in[17];
    const float* upd_g1 = (const float*)d_in[18];
    const float* upd_be1= (const float*)d_in[19];
    const float* upd_g2 = (const float*)d_in[20];
    const float* upd_be2= (const float*)d_in[21];
    const float* pred_W1= (const float*)d_in[22];
    const float* pred_b1= (const float*)d_in[23];
    const float* pred_W2= (const float*)d_in[24];
    const float* pred_b2= (const float*)d_in[25];
    float* out = (float*)d_out;

    float* ws = (float*)d_ws;
    float*     h      = ws;                         // 3.2M floats
    float*     agg    = ws + 3200000;               // 3.2M floats
    _Float16*  m2     = (_Float16*)(ws + 6400000);  // 25.6M f16 (12.8M float slots)
    int*       cnt    = (int*)(ws + 19200000);      // 25001
    int*       rowptr = cnt + 25008;                // 25001
    int*       cursor = rowptr + 25008;             // 25001
    int*       src_s  = cursor + 25008;             // 200000
    int*       dst_s  = src_s + 200000;             // 200000
    float*     dist_s = (float*)(dst_s + 200000);   // 200000
    float*     g      = dist_s + 200000;            // 8192

    // one-time CSR build (dst constant across layers)
    hipMemsetAsync(cnt, 0, 25001 * sizeof(int), stream);
    hist_kernel<<<(N_EDGES + 255) / 256, 256, 0, stream>>>(ei, cnt);
    scan_kernel<<<1, 256, 0, stream>>>(cnt, rowptr, cursor);
    scatter_kernel<<<(N_EDGES + 255) / 256, 256, 0, stream>>>(ei, pos, cursor, src_s, dst_s, dist_s);

    embed_kernel<<<4096, 256, 0, stream>>>(x, emb_W, emb_b, h);

    for (int l = 0; l < DEPTH; l++) {
        msg_kernel<<<256, 256, 0, stream>>>(
            h, dist_s, src_s, dst_s,
            msg_W1 + (size_t)l * 257 * 128, msg_b1 + l * 128, msg_g1 + l * 128, msg_be1 + l * 128,
            msg_W2 + (size_t)l * 128 * 128, msg_b2 + l * 128, msg_g2 + l * 128, msg_be2 + l * 128,
            m2);
        agg_kernel<<<N_NODES, 128, 0, stream>>>(m2, rowptr, agg);
        upd_kernel<<<196, 256, 0, stream>>>(
            h, agg,
            upd_W1 + (size_t)l * 256 * 128, upd_b1 + l * 128, upd_g1 + l * 128, upd_be1 + l * 128,
            upd_W2 + (size_t)l * 128 * 128, upd_b2 + l * 128, upd_g2 + l * 128, upd_be2 + l * 128);
    }

    pool_kernel<<<64, 128, 0, stream>>>(h, batch, g);
    pred_kernel<<<64, 128, 0, stream>>>(g, pred_W1, pred_b1, pred_W2, pred_b2, out);
}